// Round 15
// baseline (311.152 us; speedup 1.0000x reference)
//
#include <hip/hip_runtime.h>

typedef short s16x8 __attribute__((ext_vector_type(8)));
typedef float f32x4 __attribute__((ext_vector_type(4)));
typedef float f32x2 __attribute__((ext_vector_type(2)));
typedef int   i32x2 __attribute__((ext_vector_type(2)));
typedef unsigned int u32x2 __attribute__((ext_vector_type(2)));

// bf16 helpers (manual, round-to-nearest-even)
__device__ __forceinline__ unsigned short f2bf(float f) {
  unsigned int u = __float_as_uint(f);
  unsigned int r = (u + 0x7FFFu + ((u >> 16) & 1u)) >> 16;
  return (unsigned short)r;
}
__device__ __forceinline__ float bf_lo(unsigned int u) { return __uint_as_float(u << 16); }
__device__ __forceinline__ float bf_hi(unsigned int u) { return __uint_as_float(u & 0xFFFF0000u); }

// ---------------- setup (fused zero + weight transpose/convert) ----------------

__global__ void k_misc(int* __restrict__ deg, int* __restrict__ bkcnt,
                       float* __restrict__ sums,
                       const float* __restrict__ W2, unsigned short* __restrict__ wb2t,
                       const float* __restrict__ W3, unsigned short* __restrict__ wb3t,
                       int n, int G) {
  int i = blockIdx.x * 256 + threadIdx.x;
  if (i < n) deg[i] = 0;
  if (i < 8) bkcnt[i] = 0;
  if (i < G * 64) sums[i] = 0.f;
  if (i < 128 * 128) { int k = i >> 7, c = i & 127; wb2t[c * 128 + k] = f2bf(W2[i]); }
  if (i < 128 * 64)  { int k = i >> 6, c = i & 63;  wb3t[c * 128 + k] = f2bf(W3[i]); }
}

// ---------------- pass A: degree count + radix partition (fused) ----------------
__global__ __launch_bounds__(256) void k_partA(const int* __restrict__ src,
                                               const int* __restrict__ dst,
                                               int* __restrict__ deg,
                                               int* __restrict__ bkcnt,
                                               i32x2* __restrict__ stage,
                                               int e, int wsize, int cap) {
  __shared__ int hist[8];
  __shared__ int base[8];
  int i0 = blockIdx.x * 1024;
  if (threadIdx.x < 8) hist[threadIdx.x] = 0;
  __syncthreads();
  int s[4], d[4], w[4];
#pragma unroll
  for (int j = 0; j < 4; ++j) {
    int i = i0 + j * 256 + threadIdx.x;
    if (i < e) {
      s[j] = __builtin_nontemporal_load(src + i);
      d[j] = __builtin_nontemporal_load(dst + i);
      w[j] = d[j] / wsize;
      atomicAdd(&hist[w[j]], 1);
      atomicAdd(&deg[d[j]], 1);          // fused degree count
    } else w[j] = -1;
  }
  __syncthreads();
  if (threadIdx.x < 8) base[threadIdx.x] = atomicAdd(&bkcnt[threadIdx.x], hist[threadIdx.x]);
  __syncthreads();
  if (threadIdx.x < 8) hist[threadIdx.x] = 0;   // reuse as local cursor
  __syncthreads();
#pragma unroll
  for (int j = 0; j < 4; ++j) {
    if (w[j] >= 0) {
      int r = atomicAdd(&hist[w[j]], 1);
      i32x2 sd; sd.x = s[j]; sd.y = d[j];
      stage[(size_t)w[j] * cap + base[w[j]] + r] = sd;
    }
  }
}

// scan over real-edge counts (+ fused dinv / xs computation)
__global__ void k_scan1(const int* __restrict__ deg, int* __restrict__ rp,
                        int* __restrict__ psum, const float* __restrict__ x,
                        float* __restrict__ dinv, float* __restrict__ xs, int n) {
  __shared__ int s[256];
  int tid = threadIdx.x;
  int i = blockIdx.x * 256 + tid;
  int v = (i < n) ? deg[i] : 0;
  if (i < n) {
    float dv = rsqrtf((float)(v + 1));
    dinv[i] = dv;
#pragma unroll
    for (int f = 0; f < 7; ++f) xs[i * 7 + f] = x[i * 7 + f] * dv;
  }
  int xacc = v;
  s[tid] = xacc; __syncthreads();
  for (int off = 1; off < 256; off <<= 1) {
    int t = (tid >= off) ? s[tid - off] : 0;
    __syncthreads();
    xacc += t; s[tid] = xacc;
    __syncthreads();
  }
  if (i < n) rp[i] = xacc - v;              // exclusive within block
  if (tid == 255) psum[blockIdx.x] = xacc;  // block total
}

__global__ void k_scan2(int* __restrict__ psum, int nb) {
  __shared__ int s[256];
  int tid = threadIdx.x;
  int v = (tid < nb) ? psum[tid] : 0;
  int x = v;
  s[tid] = x; __syncthreads();
  for (int off = 1; off < 256; off <<= 1) {
    int t = (tid >= off) ? s[tid - off] : 0;
    __syncthreads();
    x += t; s[tid] = x;
    __syncthreads();
  }
  if (tid < nb) psum[tid] = x - v;          // exclusive prefix of block sums
}

__global__ void k_scan3(int* __restrict__ rp, int* __restrict__ cursor,
                        const int* __restrict__ psum, int n, int total) {
  int i = blockIdx.x * blockDim.x + threadIdx.x;
  if (i < n) {
    int r = rp[i] + psum[i >> 8];
    rp[i] = r;
    cursor[i] = r;
  }
  if (i == 0) rp[n] = total;
}

// Pass B: window-major scatter; each window's CSR range is compact.
__global__ __launch_bounds__(256) void k_scatB(const i32x2* __restrict__ stage,
                                               const int* __restrict__ bkcnt,
                                               int* __restrict__ cursor,
                                               int* __restrict__ csr, int cap, int nc) {
  int w = blockIdx.x & 7;
  int c = blockIdx.x >> 3;
  int cnt = bkcnt[w];
  int chunk = (cnt + nc - 1) / nc;
  int i0 = c * chunk, i1 = min(cnt, i0 + chunk);
  const i32x2* sp = stage + (size_t)w * cap;
  for (int i = i0 + threadIdx.x; i < i1; i += 256) {
    i32x2 sd = __builtin_nontemporal_load(sp + i);
    int pos = atomicAdd(&cursor[sd.y], 1);
    csr[pos] = sd.x;
  }
}

// ---------------- aggregation (pull, CSR by dst) ----------------

// FUSED layer-1: agg7 + gemm1. Wave per node; lanes gather edges and
// butterfly-reduce (every lane ends with the full 7-vector), then each lane
// computes 2 output columns from LDS-resident W1. relu + dinv scale -> bf16.
__global__ __launch_bounds__(256) void k_agg7g1(const float* __restrict__ xs,
                                                const int* __restrict__ csr,
                                                const int* __restrict__ rp,
                                                const float* __restrict__ dinv,
                                                const float* __restrict__ W1,
                                                const float* __restrict__ b1,
                                                unsigned short* __restrict__ out, int n) {
  __shared__ float ws[7 * 128];
  for (int j = threadIdx.x; j < 7 * 128; j += 256) ws[j] = W1[j];
  __syncthreads();
  int wave = threadIdx.x >> 6, lane = threadIdx.x & 63;
  int v = blockIdx.x * 4 + wave;
  if (v >= n) return;
  int beg = rp[v], end = rp[v + 1];
  float a[7] = {0.f, 0.f, 0.f, 0.f, 0.f, 0.f, 0.f};
  for (int base = beg; base < end; base += 64) {
    int cnt = end - base; if (cnt > 64) cnt = 64;
    if (lane < cnt) {
      int s = __builtin_nontemporal_load(csr + base + lane);
      const float* xr = xs + (size_t)s * 7;
#pragma unroll
      for (int f = 0; f < 7; ++f) a[f] += xr[f];
    }
  }
#pragma unroll
  for (int off = 32; off > 0; off >>= 1) {
#pragma unroll
    for (int f = 0; f < 7; ++f) a[f] += __shfl_xor(a[f], off);
  }
  float dv = dinv[v];
#pragma unroll
  for (int f = 0; f < 7; ++f) a[f] = dv * (a[f] + xs[(size_t)v * 7 + f]);
  int c = lane * 2;
  float acc0 = b1[c], acc1 = b1[c + 1];
#pragma unroll
  for (int f = 0; f < 7; ++f) {
    acc0 += a[f] * ws[f * 128 + c];
    acc1 += a[f] * ws[f * 128 + c + 1];
  }
  unsigned int o = (unsigned int)f2bf(fmaxf(acc0, 0.f) * dv)
                 | ((unsigned int)f2bf(fmaxf(acc1, 0.f) * dv) << 16);
  ((unsigned int*)out)[(size_t)v * 64 + lane] = o;
}

// width-128 bf16 aggregation, SLICE-RESIDENT: one 64B column-slice (cg) per
// LAUNCH -- whole chip touches only 3.2 MB -> fits every XCD L2. 16 lanes/node,
// u32 (2 bf16)/lane. fp32 accumulate; nt store (protect slice residency).
__global__ void k_agg128s(const unsigned short* __restrict__ t, const int* __restrict__ csr,
                          const int* __restrict__ rp, const float* __restrict__ dinv,
                          unsigned short* __restrict__ out, int n, int cg) {
  int gid = blockIdx.x * blockDim.x + threadIdx.x;
  int v = gid >> 4, lane = gid & 15;
  if (v >= n) return;
  int beg = rp[v], end = rp[v + 1];
  float a0 = 0.f, a1 = 0.f;
  const unsigned int* tp = (const unsigned int*)t + cg * 16 + lane;  // row stride 64 u32
  for (int base = beg; base < end; base += 16) {
    int cnt = end - base; if (cnt > 16) cnt = 16;
    int ee = __builtin_nontemporal_load(csr + base + (lane < cnt ? lane : cnt - 1));
    int j = 0;
    for (; j + 4 <= cnt; j += 4) {
      int s0 = __shfl(ee, j + 0, 16), s1 = __shfl(ee, j + 1, 16);
      int s2 = __shfl(ee, j + 2, 16), s3 = __shfl(ee, j + 3, 16);
      unsigned int r0 = tp[(size_t)s0 * 64];
      unsigned int r1 = tp[(size_t)s1 * 64];
      unsigned int r2 = tp[(size_t)s2 * 64];
      unsigned int r3 = tp[(size_t)s3 * 64];
      a0 += bf_lo(r0); a1 += bf_hi(r0);
      a0 += bf_lo(r1); a1 += bf_hi(r1);
      a0 += bf_lo(r2); a1 += bf_hi(r2);
      a0 += bf_lo(r3); a1 += bf_hi(r3);
    }
    for (; j < cnt; ++j) {
      int s0 = __shfl(ee, j, 16);
      unsigned int r0 = tp[(size_t)s0 * 64];
      a0 += bf_lo(r0); a1 += bf_hi(r0);
    }
  }
  // self term
  {
    unsigned int r = tp[(size_t)v * 64];
    a0 += bf_lo(r); a1 += bf_hi(r);
  }
  float dv = dinv[v];
  unsigned int o = (unsigned int)f2bf(a0 * dv) | ((unsigned int)f2bf(a1 * dv) << 16);
  __builtin_nontemporal_store(o, (unsigned int*)out + (size_t)v * 64 + cg * 16 + lane);
}

// width-64 bf16 aggregation + bias, SLICE-RESIDENT x2 (3.2 MB slices).
__global__ void k_agg64bs(const unsigned short* __restrict__ t, const int* __restrict__ csr,
                          const int* __restrict__ rp, const float* __restrict__ dinv,
                          const float* __restrict__ bias, float* __restrict__ out,
                          int n, int cg) {
  int gid = blockIdx.x * blockDim.x + threadIdx.x;
  int v = gid >> 4, lane = gid & 15;
  if (v >= n) return;
  int beg = rp[v], end = rp[v + 1];
  float a0 = 0.f, a1 = 0.f;
  const unsigned int* tp = (const unsigned int*)t + cg * 16 + lane;  // row stride 32 u32
  for (int base = beg; base < end; base += 16) {
    int cnt = end - base; if (cnt > 16) cnt = 16;
    int ee = __builtin_nontemporal_load(csr + base + (lane < cnt ? lane : cnt - 1));
    int j = 0;
    for (; j + 4 <= cnt; j += 4) {
      int s0 = __shfl(ee, j + 0, 16), s1 = __shfl(ee, j + 1, 16);
      int s2 = __shfl(ee, j + 2, 16), s3 = __shfl(ee, j + 3, 16);
      unsigned int r0 = tp[(size_t)s0 * 32];
      unsigned int r1 = tp[(size_t)s1 * 32];
      unsigned int r2 = tp[(size_t)s2 * 32];
      unsigned int r3 = tp[(size_t)s3 * 32];
      a0 += bf_lo(r0); a1 += bf_hi(r0);
      a0 += bf_lo(r1); a1 += bf_hi(r1);
      a0 += bf_lo(r2); a1 += bf_hi(r2);
      a0 += bf_lo(r3); a1 += bf_hi(r3);
    }
    for (; j < cnt; ++j) {
      int s0 = __shfl(ee, j, 16);
      unsigned int r0 = tp[(size_t)s0 * 32];
      a0 += bf_lo(r0); a1 += bf_hi(r0);
    }
  }
  // self term
  {
    unsigned int r = tp[(size_t)v * 32];
    a0 += bf_lo(r); a1 += bf_hi(r);
  }
  float dv = dinv[v];
  const float2 b2 = *((const float2*)bias + cg * 16 + lane);
  f32x2 o;
  o.x = a0 * dv + b2.x;
  o.y = a1 * dv + b2.y;
  __builtin_nontemporal_store(o, (f32x2*)(out + (size_t)v * 64) + cg * 16 + lane);
}

// ---------------- GEMMs ----------------

// MFMA gemm2: [n,128]bf16 @ W2 + b2, relu -> [n,128]bf16.
__global__ __launch_bounds__(256) void k_gemm2(const unsigned short* __restrict__ A,
                                               const unsigned short* __restrict__ Bt,
                                               const float* __restrict__ bias,
                                               unsigned short* __restrict__ out, int n) {
  int wave = threadIdx.x >> 6, lane = threadIdx.x & 63;
  int am = lane & 15, kg = lane >> 4;
  int r0 = blockIdx.x * 64 + wave * 16;
  int arow = min(r0 + am, n - 1);
  const unsigned short* ap = A + (size_t)arow * 128 + kg * 8;
  f32x4 acc[8] = {};
#pragma unroll
  for (int kb = 0; kb < 4; ++kb) {
    s16x8 a = *(const s16x8*)(ap + kb * 32);
#pragma unroll
    for (int c = 0; c < 8; ++c) {
      s16x8 b = *(const s16x8*)(Bt + (size_t)(c * 16 + am) * 128 + kb * 32 + kg * 8);
      acc[c] = __builtin_amdgcn_mfma_f32_16x16x32_bf16(a, b, acc[c], 0, 0, 0);
    }
  }
#pragma unroll
  for (int c = 0; c < 8; ++c) {
    float bb = bias[c * 16 + am];
#pragma unroll
    for (int j = 0; j < 4; ++j) {
      int r = r0 + kg * 4 + j;
      if (r < n) out[(size_t)r * 128 + c * 16 + am] = f2bf(fmaxf(acc[c][j] + bb, 0.f));
    }
  }
}

// MFMA gemm3: [n,128]bf16 @ W3, row-scale by dinv -> [n,64]bf16 (feeds agg64b).
__global__ __launch_bounds__(256) void k_gemm3(const unsigned short* __restrict__ A,
                                               const unsigned short* __restrict__ Bt,
                                               const float* __restrict__ dinv,
                                               unsigned short* __restrict__ out, int n) {
  int wave = threadIdx.x >> 6, lane = threadIdx.x & 63;
  int am = lane & 15, kg = lane >> 4;
  int r0 = blockIdx.x * 64 + wave * 16;
  int arow = min(r0 + am, n - 1);
  const unsigned short* ap = A + (size_t)arow * 128 + kg * 8;
  f32x4 acc[4] = {};
#pragma unroll
  for (int kb = 0; kb < 4; ++kb) {
    s16x8 a = *(const s16x8*)(ap + kb * 32);
#pragma unroll
    for (int c = 0; c < 4; ++c) {
      s16x8 b = *(const s16x8*)(Bt + (size_t)(c * 16 + am) * 128 + kb * 32 + kg * 8);
      acc[c] = __builtin_amdgcn_mfma_f32_16x16x32_bf16(a, b, acc[c], 0, 0, 0);
    }
  }
  float dv[4];
#pragma unroll
  for (int j = 0; j < 4; ++j) dv[j] = dinv[min(r0 + kg * 4 + j, n - 1)];
#pragma unroll
  for (int c = 0; c < 4; ++c) {
#pragma unroll
    for (int j = 0; j < 4; ++j) {
      int r = r0 + kg * 4 + j;
      if (r < n) out[(size_t)r * 64 + c * 16 + am] = f2bf(acc[c][j] * dv[j]);
    }
  }
}

// ---------------- mean pool over sorted batch (node-parallel) ----------------

__global__ void k_pool1(const float* __restrict__ h, const int* __restrict__ batch,
                        float* __restrict__ sums, int n) {
  int gid = blockIdx.x * blockDim.x + threadIdx.x;
  int w = gid >> 6, f = gid & 63;
  int i0 = w * 16;
  if (i0 >= n) return;
  int i1 = min(i0 + 16, n);
  int cur = batch[i0];
  float acc = 0.f;
  for (int i = i0; i < i1; ++i) {
    int g = batch[i];
    if (g != cur) {
      atomicAdd(&sums[cur * 64 + f], acc);
      acc = 0.f; cur = g;
    }
    acc += h[(size_t)i * 64 + f];
  }
  atomicAdd(&sums[cur * 64 + f], acc);
}

__global__ void k_pool2(const float* __restrict__ sums, const int* __restrict__ batch,
                        float* __restrict__ pooled, int n) {
  int g = blockIdx.x, f = threadIdx.x;
  int lo = 0, hi = n;
  while (lo < hi) { int m = (lo + hi) >> 1; if (batch[m] < g) lo = m + 1; else hi = m; }
  int start = lo;
  hi = n;
  while (lo < hi) { int m = (lo + hi) >> 1; if (batch[m] < g + 1) lo = m + 1; else hi = m; }
  float cnt = (float)(lo - start);
  pooled[g * 64 + f] = sums[g * 64 + f] / fmaxf(cnt, 1.f);
}

// ---------------- launch ----------------

extern "C" void kernel_launch(void* const* d_in, const int* in_sizes, int n_in,
                              void* d_out, int out_size, void* d_ws, size_t ws_size,
                              hipStream_t stream) {
  const float* x   = (const float*)d_in[0];
  const int* eidx  = (const int*)d_in[1];
  const int* batch = (const int*)d_in[2];
  const float* W1  = (const float*)d_in[3];
  const float* b1  = (const float*)d_in[4];
  const float* W2  = (const float*)d_in[5];
  const float* b2  = (const float*)d_in[6];
  const float* W3  = (const float*)d_in[7];
  const float* b3  = (const float*)d_in[8];
  float* out = (float*)d_out;

  const int n = in_sizes[0] / 7;       // 50000
  const int e = in_sizes[1] / 2;       // 800000
  const int G = out_size / 64 - n;     // 50
  const int CAP = 131072;              // staging capacity per window bucket

  // workspace carve-up (4B elements)
  float* wsf = (float*)d_ws;
  int*   wsi = (int*)d_ws;
  size_t off = 0;
  int*   deg    = wsi + off; off += n;
  float* dinv   = wsf + off; off += n;
  int*   rp     = wsi + off; off += (size_t)((n + 1 + 3) & ~3);
  int*   cursor = wsi + off; off += n;
  int*   psum   = wsi + off; off += 256;
  int*   bkcnt  = wsi + off; off += 8;
  float* sums   = wsf + off; off += (size_t)G * 64;
  unsigned short* wb2t = (unsigned short*)(wsf + off); off += 128 * 128 / 2;  // bf16 W2^T
  unsigned short* wb3t = (unsigned short*)(wsf + off); off += 128 * 64 / 2;   // bf16 W3^T
  int*   csr    = wsi + off; off += (size_t)((e + 3) & ~3);
  float* xs     = wsf + off; off += (size_t)((n * 7 + 3) & ~3);
  off = (off + 3) & ~(size_t)3;
  i32x2* stage  = (i32x2*)(wsi + off); off += (size_t)8 * CAP * 2;
  float* bufA   = wsf + off; off += (size_t)n * 128;
  float* bufB   = wsf + off; off += (size_t)n * 128;

  // bf16 tensors alias fp32 buffers (dataflow strictly serialized):
  unsigned short* t2 = (unsigned short*)bufB;   // agg7g1 out (dinv-scaled)
  unsigned short* a2 = (unsigned short*)bufA;   // agg128 out
  unsigned short* h2 = (unsigned short*)bufB;   // gemm2 out
  unsigned short* t3 = (unsigned short*)bufA;   // gemm3 out (dinv-scaled)

  const int* src = eidx;       // edge_index[0]
  const int* dst = eidx + e;   // edge_index[1]

  const int nb = (n + 255) / 256;
  const int wsize = (n + 7) / 8;

  // setup + CSR build (fused count+partition, then scan, then windowed scatter)
  k_misc<<<nb, 256, 0, stream>>>(deg, bkcnt, sums, W2, wb2t, W3, wb3t, n, G);
  k_partA<<<(e + 1023) / 1024, 256, 0, stream>>>(src, dst, deg, bkcnt, stage, e, wsize, CAP);
  k_scan1<<<nb, 256, 0, stream>>>(deg, rp, psum, x, dinv, xs, n);
  k_scan2<<<1, 256, 0, stream>>>(psum, nb);
  k_scan3<<<nb, 256, 0, stream>>>(rp, cursor, psum, n, e);
  const int nc = 128;
  k_scatB<<<8 * nc, 256, 0, stream>>>(stage, bkcnt, cursor, csr, CAP, nc);

  // layer 1 (fused): AGG(xs) + @W1 + b1, relu, dinv-scale -> bf16 t2
  k_agg7g1<<<(n + 3) / 4, 256, 0, stream>>>(xs, csr, rp, dinv, W1, b1, t2, n);

  // layer 2: AGG(t2) slice-resident x4 -> a2 bf16, then MFMA @W2 + b2, relu -> h2
  {
    const int gb = ((size_t)n * 16 + 255) / 256;
    for (int cg = 0; cg < 4; ++cg)
      k_agg128s<<<gb, 256, 0, stream>>>(t2, csr, rp, dinv, a2, n, cg);
  }
  k_gemm2<<<(n + 63) / 64, 256, 0, stream>>>(a2, wb2t, b2, h2, n);

  // layer 3: MFMA h2 @ W3, dinv-scale -> t3 bf16, then AGG slice-resident x2 -> d_out
  k_gemm3<<<(n + 63) / 64, 256, 0, stream>>>(h2, wb3t, dinv, t3, n);
  {
    const int gb = ((size_t)n * 16 + 255) / 256;
    for (int cg = 0; cg < 2; ++cg)
      k_agg64bs<<<gb, 256, 0, stream>>>(t3, csr, rp, dinv, b3, out, n, cg);
  }

  // mean pool -> d_out tail (node-parallel + finalize)
  const int waves = (n + 15) / 16;
  k_pool1<<<(waves * 64 + 255) / 256, 256, 0, stream>>>(out, batch, sums, n);
  k_pool2<<<G, 64, 0, stream>>>(sums, batch, out + (size_t)n * 64, n);
}

// Round 16
// 242.167 us; speedup vs baseline: 1.2849x; 1.2849x over previous
//
#include <hip/hip_runtime.h>

typedef short s16x8 __attribute__((ext_vector_type(8)));
typedef float f32x4 __attribute__((ext_vector_type(4)));
typedef int   i32x2 __attribute__((ext_vector_type(2)));
typedef unsigned int u32x2 __attribute__((ext_vector_type(2)));

// bf16 helpers (manual, round-to-nearest-even)
__device__ __forceinline__ unsigned short f2bf(float f) {
  unsigned int u = __float_as_uint(f);
  unsigned int r = (u + 0x7FFFu + ((u >> 16) & 1u)) >> 16;
  return (unsigned short)r;
}
__device__ __forceinline__ float bf_lo(unsigned int u) { return __uint_as_float(u << 16); }
__device__ __forceinline__ float bf_hi(unsigned int u) { return __uint_as_float(u & 0xFFFF0000u); }

// ---------------- setup (fused zero + weight transpose/convert) ----------------

__global__ void k_misc(int* __restrict__ deg, int* __restrict__ bkcnt,
                       float* __restrict__ sums,
                       const float* __restrict__ W2, unsigned short* __restrict__ wb2t,
                       const float* __restrict__ W3, unsigned short* __restrict__ wb3t,
                       int n, int G) {
  int i = blockIdx.x * 256 + threadIdx.x;
  if (i < n) deg[i] = 0;
  if (i < 8) bkcnt[i] = 0;
  if (i < G * 64) sums[i] = 0.f;
  if (i < 128 * 128) { int k = i >> 7, c = i & 127; wb2t[c * 128 + k] = f2bf(W2[i]); }
  if (i < 128 * 64)  { int k = i >> 6, c = i & 63;  wb3t[c * 128 + k] = f2bf(W3[i]); }
}

// ---------------- pass A: degree count + radix partition (fused) ----------------
__global__ __launch_bounds__(256) void k_partA(const int* __restrict__ src,
                                               const int* __restrict__ dst,
                                               int* __restrict__ deg,
                                               int* __restrict__ bkcnt,
                                               i32x2* __restrict__ stage,
                                               int e, int wsize, int cap) {
  __shared__ int hist[8];
  __shared__ int base[8];
  int i0 = blockIdx.x * 1024;
  if (threadIdx.x < 8) hist[threadIdx.x] = 0;
  __syncthreads();
  int s[4], d[4], w[4];
#pragma unroll
  for (int j = 0; j < 4; ++j) {
    int i = i0 + j * 256 + threadIdx.x;
    if (i < e) {
      s[j] = __builtin_nontemporal_load(src + i);
      d[j] = __builtin_nontemporal_load(dst + i);
      w[j] = d[j] / wsize;
      atomicAdd(&hist[w[j]], 1);
      atomicAdd(&deg[d[j]], 1);          // fused degree count
    } else w[j] = -1;
  }
  __syncthreads();
  if (threadIdx.x < 8) base[threadIdx.x] = atomicAdd(&bkcnt[threadIdx.x], hist[threadIdx.x]);
  __syncthreads();
  if (threadIdx.x < 8) hist[threadIdx.x] = 0;   // reuse as local cursor
  __syncthreads();
#pragma unroll
  for (int j = 0; j < 4; ++j) {
    if (w[j] >= 0) {
      int r = atomicAdd(&hist[w[j]], 1);
      i32x2 sd; sd.x = s[j]; sd.y = d[j];
      stage[(size_t)w[j] * cap + base[w[j]] + r] = sd;
    }
  }
}

// scan over real-edge counts (+ fused dinv / xs computation)
__global__ void k_scan1(const int* __restrict__ deg, int* __restrict__ rp,
                        int* __restrict__ psum, const float* __restrict__ x,
                        float* __restrict__ dinv, float* __restrict__ xs, int n) {
  __shared__ int s[256];
  int tid = threadIdx.x;
  int i = blockIdx.x * 256 + tid;
  int v = (i < n) ? deg[i] : 0;
  if (i < n) {
    float dv = rsqrtf((float)(v + 1));
    dinv[i] = dv;
#pragma unroll
    for (int f = 0; f < 7; ++f) xs[i * 7 + f] = x[i * 7 + f] * dv;
  }
  int xacc = v;
  s[tid] = xacc; __syncthreads();
  for (int off = 1; off < 256; off <<= 1) {
    int t = (tid >= off) ? s[tid - off] : 0;
    __syncthreads();
    xacc += t; s[tid] = xacc;
    __syncthreads();
  }
  if (i < n) rp[i] = xacc - v;              // exclusive within block
  if (tid == 255) psum[blockIdx.x] = xacc;  // block total
}

__global__ void k_scan2(int* __restrict__ psum, int nb) {
  __shared__ int s[256];
  int tid = threadIdx.x;
  int v = (tid < nb) ? psum[tid] : 0;
  int x = v;
  s[tid] = x; __syncthreads();
  for (int off = 1; off < 256; off <<= 1) {
    int t = (tid >= off) ? s[tid - off] : 0;
    __syncthreads();
    x += t; s[tid] = x;
    __syncthreads();
  }
  if (tid < nb) psum[tid] = x - v;          // exclusive prefix of block sums
}

__global__ void k_scan3(int* __restrict__ rp, int* __restrict__ cursor,
                        const int* __restrict__ psum, int n, int total) {
  int i = blockIdx.x * blockDim.x + threadIdx.x;
  if (i < n) {
    int r = rp[i] + psum[i >> 8];
    rp[i] = r;
    cursor[i] = r;
  }
  if (i == 0) rp[n] = total;
}

// Pass B: window-major scatter; each window's CSR range is compact.
__global__ __launch_bounds__(256) void k_scatB(const i32x2* __restrict__ stage,
                                               const int* __restrict__ bkcnt,
                                               int* __restrict__ cursor,
                                               int* __restrict__ csr, int cap, int nc) {
  int w = blockIdx.x & 7;
  int c = blockIdx.x >> 3;
  int cnt = bkcnt[w];
  int chunk = (cnt + nc - 1) / nc;
  int i0 = c * chunk, i1 = min(cnt, i0 + chunk);
  const i32x2* sp = stage + (size_t)w * cap;
  for (int i = i0 + threadIdx.x; i < i1; i += 256) {
    i32x2 sd = __builtin_nontemporal_load(sp + i);
    int pos = atomicAdd(&cursor[sd.y], 1);
    csr[pos] = sd.x;
  }
}

// ---------------- aggregation (pull, CSR by dst) ----------------

// FUSED layer-1: agg7 + gemm1. Wave per node; lanes gather edges and
// butterfly-reduce (every lane ends with the full 7-vector), then each lane
// computes 2 output columns from LDS-resident W1. relu + dinv scale -> bf16.
__global__ __launch_bounds__(256) void k_agg7g1(const float* __restrict__ xs,
                                                const int* __restrict__ csr,
                                                const int* __restrict__ rp,
                                                const float* __restrict__ dinv,
                                                const float* __restrict__ W1,
                                                const float* __restrict__ b1,
                                                unsigned short* __restrict__ out, int n) {
  __shared__ float ws[7 * 128];
  for (int j = threadIdx.x; j < 7 * 128; j += 256) ws[j] = W1[j];
  __syncthreads();
  int wave = threadIdx.x >> 6, lane = threadIdx.x & 63;
  int v = blockIdx.x * 4 + wave;
  if (v >= n) return;
  int beg = rp[v], end = rp[v + 1];
  float a[7] = {0.f, 0.f, 0.f, 0.f, 0.f, 0.f, 0.f};
  for (int base = beg; base < end; base += 64) {
    int cnt = end - base; if (cnt > 64) cnt = 64;
    if (lane < cnt) {
      int s = __builtin_nontemporal_load(csr + base + lane);
      const float* xr = xs + (size_t)s * 7;
#pragma unroll
      for (int f = 0; f < 7; ++f) a[f] += xr[f];
    }
  }
#pragma unroll
  for (int off = 32; off > 0; off >>= 1) {
#pragma unroll
    for (int f = 0; f < 7; ++f) a[f] += __shfl_xor(a[f], off);
  }
  float dv = dinv[v];
#pragma unroll
  for (int f = 0; f < 7; ++f) a[f] = dv * (a[f] + xs[(size_t)v * 7 + f]);
  int c = lane * 2;
  float acc0 = b1[c], acc1 = b1[c + 1];
#pragma unroll
  for (int f = 0; f < 7; ++f) {
    acc0 += a[f] * ws[f * 128 + c];
    acc1 += a[f] * ws[f * 128 + c + 1];
  }
  unsigned int o = (unsigned int)f2bf(fmaxf(acc0, 0.f) * dv)
                 | ((unsigned int)f2bf(fmaxf(acc1, 0.f) * dv) << 16);
  ((unsigned int*)out)[(size_t)v * 64 + lane] = o;
}

// width-128 bf16 aggregation: 32 lanes/node, u32x2 (4 bf16)/lane.
// fp32 accumulate; out = bf16(dinv[d] * (sum + own_row)).  Plain store
// (consumed by gemm2 next -- keep in L2).
__global__ void k_agg128(const unsigned short* __restrict__ t, const int* __restrict__ csr,
                         const int* __restrict__ rp, const float* __restrict__ dinv,
                         unsigned short* __restrict__ out, int n) {
  int gid = blockIdx.x * blockDim.x + threadIdx.x;
  int v = gid >> 5, lane = gid & 31;
  if (v >= n) return;
  int beg = rp[v], end = rp[v + 1];
  float4 a = make_float4(0.f, 0.f, 0.f, 0.f);
  const u32x2* tp = (const u32x2*)t + lane;   // row stride = 32 u32x2 (128 bf16)
  for (int base = beg; base < end; base += 32) {
    int cnt = end - base; if (cnt > 32) cnt = 32;
    int ee = __builtin_nontemporal_load(csr + base + (lane < cnt ? lane : cnt - 1));
    int j = 0;
    for (; j + 4 <= cnt; j += 4) {
      int s0 = __shfl(ee, j + 0, 32), s1 = __shfl(ee, j + 1, 32);
      int s2 = __shfl(ee, j + 2, 32), s3 = __shfl(ee, j + 3, 32);
      u32x2 r0 = tp[(size_t)s0 * 32];
      u32x2 r1 = tp[(size_t)s1 * 32];
      u32x2 r2 = tp[(size_t)s2 * 32];
      u32x2 r3 = tp[(size_t)s3 * 32];
      a.x += bf_lo(r0.x); a.y += bf_hi(r0.x); a.z += bf_lo(r0.y); a.w += bf_hi(r0.y);
      a.x += bf_lo(r1.x); a.y += bf_hi(r1.x); a.z += bf_lo(r1.y); a.w += bf_hi(r1.y);
      a.x += bf_lo(r2.x); a.y += bf_hi(r2.x); a.z += bf_lo(r2.y); a.w += bf_hi(r2.y);
      a.x += bf_lo(r3.x); a.y += bf_hi(r3.x); a.z += bf_lo(r3.y); a.w += bf_hi(r3.y);
    }
    for (; j < cnt; ++j) {
      int s0 = __shfl(ee, j, 32);
      u32x2 r0 = tp[(size_t)s0 * 32];
      a.x += bf_lo(r0.x); a.y += bf_hi(r0.x); a.z += bf_lo(r0.y); a.w += bf_hi(r0.y);
    }
  }
  // self term (coalesced)
  {
    u32x2 r = tp[(size_t)v * 32];
    a.x += bf_lo(r.x); a.y += bf_hi(r.x); a.z += bf_lo(r.y); a.w += bf_hi(r.y);
  }
  float dv = dinv[v];
  u32x2 o;
  o.x = (unsigned int)f2bf(a.x * dv) | ((unsigned int)f2bf(a.y * dv) << 16);
  o.y = (unsigned int)f2bf(a.z * dv) | ((unsigned int)f2bf(a.w * dv) << 16);
  *((u32x2*)(out + (size_t)v * 128) + lane) = o;
}

// width-64 bf16 aggregation + bias: 16 lanes/node. Plain store (consumed by pool).
__global__ void k_agg64b(const unsigned short* __restrict__ t, const int* __restrict__ csr,
                         const int* __restrict__ rp, const float* __restrict__ dinv,
                         const float* __restrict__ bias, float* __restrict__ out, int n) {
  int gid = blockIdx.x * blockDim.x + threadIdx.x;
  int v = gid >> 4, lane = gid & 15;
  if (v >= n) return;
  int beg = rp[v], end = rp[v + 1];
  float4 a = make_float4(0.f, 0.f, 0.f, 0.f);
  const u32x2* tp = (const u32x2*)t + lane;   // row stride = 16 u32x2 (64 bf16)
  for (int base = beg; base < end; base += 16) {
    int cnt = end - base; if (cnt > 16) cnt = 16;
    int ee = __builtin_nontemporal_load(csr + base + (lane < cnt ? lane : cnt - 1));
    int j = 0;
    for (; j + 4 <= cnt; j += 4) {
      int s0 = __shfl(ee, j + 0, 16), s1 = __shfl(ee, j + 1, 16);
      int s2 = __shfl(ee, j + 2, 16), s3 = __shfl(ee, j + 3, 16);
      u32x2 r0 = tp[(size_t)s0 * 16];
      u32x2 r1 = tp[(size_t)s1 * 16];
      u32x2 r2 = tp[(size_t)s2 * 16];
      u32x2 r3 = tp[(size_t)s3 * 16];
      a.x += bf_lo(r0.x); a.y += bf_hi(r0.x); a.z += bf_lo(r0.y); a.w += bf_hi(r0.y);
      a.x += bf_lo(r1.x); a.y += bf_hi(r1.x); a.z += bf_lo(r1.y); a.w += bf_hi(r1.y);
      a.x += bf_lo(r2.x); a.y += bf_hi(r2.x); a.z += bf_lo(r2.y); a.w += bf_hi(r2.y);
      a.x += bf_lo(r3.x); a.y += bf_hi(r3.x); a.z += bf_lo(r3.y); a.w += bf_hi(r3.y);
    }
    for (; j < cnt; ++j) {
      int s0 = __shfl(ee, j, 16);
      u32x2 r0 = tp[(size_t)s0 * 16];
      a.x += bf_lo(r0.x); a.y += bf_hi(r0.x); a.z += bf_lo(r0.y); a.w += bf_hi(r0.y);
    }
  }
  // self term (coalesced)
  {
    u32x2 r = tp[(size_t)v * 16];
    a.x += bf_lo(r.x); a.y += bf_hi(r.x); a.z += bf_lo(r.y); a.w += bf_hi(r.y);
  }
  float dv = dinv[v];
  const float4 b4 = ((const float4*)bias)[lane];
  float4 o = make_float4(a.x * dv + b4.x, a.y * dv + b4.y,
                         a.z * dv + b4.z, a.w * dv + b4.w);
  *((float4*)(out + (size_t)v * 64) + lane) = o;
}

// ---------------- GEMMs ----------------

// MFMA gemm2: [n,128]bf16 @ W2 + b2, relu -> [n,128]bf16.
__global__ __launch_bounds__(256) void k_gemm2(const unsigned short* __restrict__ A,
                                               const unsigned short* __restrict__ Bt,
                                               const float* __restrict__ bias,
                                               unsigned short* __restrict__ out, int n) {
  int wave = threadIdx.x >> 6, lane = threadIdx.x & 63;
  int am = lane & 15, kg = lane >> 4;
  int r0 = blockIdx.x * 64 + wave * 16;
  int arow = min(r0 + am, n - 1);
  const unsigned short* ap = A + (size_t)arow * 128 + kg * 8;
  f32x4 acc[8] = {};
#pragma unroll
  for (int kb = 0; kb < 4; ++kb) {
    s16x8 a = *(const s16x8*)(ap + kb * 32);
#pragma unroll
    for (int c = 0; c < 8; ++c) {
      s16x8 b = *(const s16x8*)(Bt + (size_t)(c * 16 + am) * 128 + kb * 32 + kg * 8);
      acc[c] = __builtin_amdgcn_mfma_f32_16x16x32_bf16(a, b, acc[c], 0, 0, 0);
    }
  }
#pragma unroll
  for (int c = 0; c < 8; ++c) {
    float bb = bias[c * 16 + am];
#pragma unroll
    for (int j = 0; j < 4; ++j) {
      int r = r0 + kg * 4 + j;
      if (r < n) out[(size_t)r * 128 + c * 16 + am] = f2bf(fmaxf(acc[c][j] + bb, 0.f));
    }
  }
}

// MFMA gemm3: [n,128]bf16 @ W3, row-scale by dinv -> [n,64]bf16 (feeds agg64b).
__global__ __launch_bounds__(256) void k_gemm3(const unsigned short* __restrict__ A,
                                               const unsigned short* __restrict__ Bt,
                                               const float* __restrict__ dinv,
                                               unsigned short* __restrict__ out, int n) {
  int wave = threadIdx.x >> 6, lane = threadIdx.x & 63;
  int am = lane & 15, kg = lane >> 4;
  int r0 = blockIdx.x * 64 + wave * 16;
  int arow = min(r0 + am, n - 1);
  const unsigned short* ap = A + (size_t)arow * 128 + kg * 8;
  f32x4 acc[4] = {};
#pragma unroll
  for (int kb = 0; kb < 4; ++kb) {
    s16x8 a = *(const s16x8*)(ap + kb * 32);
#pragma unroll
    for (int c = 0; c < 4; ++c) {
      s16x8 b = *(const s16x8*)(Bt + (size_t)(c * 16 + am) * 128 + kb * 32 + kg * 8);
      acc[c] = __builtin_amdgcn_mfma_f32_16x16x32_bf16(a, b, acc[c], 0, 0, 0);
    }
  }
  float dv[4];
#pragma unroll
  for (int j = 0; j < 4; ++j) dv[j] = dinv[min(r0 + kg * 4 + j, n - 1)];
#pragma unroll
  for (int c = 0; c < 4; ++c) {
#pragma unroll
    for (int j = 0; j < 4; ++j) {
      int r = r0 + kg * 4 + j;
      if (r < n) out[(size_t)r * 64 + c * 16 + am] = f2bf(acc[c][j] * dv[j]);
    }
  }
}

// ---------------- mean pool over sorted batch (node-parallel) ----------------

__global__ void k_pool1(const float* __restrict__ h, const int* __restrict__ batch,
                        float* __restrict__ sums, int n) {
  int gid = blockIdx.x * blockDim.x + threadIdx.x;
  int w = gid >> 6, f = gid & 63;
  int i0 = w * 16;
  if (i0 >= n) return;
  int i1 = min(i0 + 16, n);
  int cur = batch[i0];
  float acc = 0.f;
  for (int i = i0; i < i1; ++i) {
    int g = batch[i];
    if (g != cur) {
      atomicAdd(&sums[cur * 64 + f], acc);
      acc = 0.f; cur = g;
    }
    acc += h[(size_t)i * 64 + f];
  }
  atomicAdd(&sums[cur * 64 + f], acc);
}

__global__ void k_pool2(const float* __restrict__ sums, const int* __restrict__ batch,
                        float* __restrict__ pooled, int n) {
  int g = blockIdx.x, f = threadIdx.x;
  int lo = 0, hi = n;
  while (lo < hi) { int m = (lo + hi) >> 1; if (batch[m] < g) lo = m + 1; else hi = m; }
  int start = lo;
  hi = n;
  while (lo < hi) { int m = (lo + hi) >> 1; if (batch[m] < g + 1) lo = m + 1; else hi = m; }
  float cnt = (float)(lo - start);
  pooled[g * 64 + f] = sums[g * 64 + f] / fmaxf(cnt, 1.f);
}

// ---------------- launch ----------------

extern "C" void kernel_launch(void* const* d_in, const int* in_sizes, int n_in,
                              void* d_out, int out_size, void* d_ws, size_t ws_size,
                              hipStream_t stream) {
  const float* x   = (const float*)d_in[0];
  const int* eidx  = (const int*)d_in[1];
  const int* batch = (const int*)d_in[2];
  const float* W1  = (const float*)d_in[3];
  const float* b1  = (const float*)d_in[4];
  const float* W2  = (const float*)d_in[5];
  const float* b2  = (const float*)d_in[6];
  const float* W3  = (const float*)d_in[7];
  const float* b3  = (const float*)d_in[8];
  float* out = (float*)d_out;

  const int n = in_sizes[0] / 7;       // 50000
  const int e = in_sizes[1] / 2;       // 800000
  const int G = out_size / 64 - n;     // 50
  const int CAP = 131072;              // staging capacity per window bucket

  // workspace carve-up (4B elements)
  float* wsf = (float*)d_ws;
  int*   wsi = (int*)d_ws;
  size_t off = 0;
  int*   deg    = wsi + off; off += n;
  float* dinv   = wsf + off; off += n;
  int*   rp     = wsi + off; off += (size_t)((n + 1 + 3) & ~3);
  int*   cursor = wsi + off; off += n;
  int*   psum   = wsi + off; off += 256;
  int*   bkcnt  = wsi + off; off += 8;
  float* sums   = wsf + off; off += (size_t)G * 64;
  unsigned short* wb2t = (unsigned short*)(wsf + off); off += 128 * 128 / 2;  // bf16 W2^T
  unsigned short* wb3t = (unsigned short*)(wsf + off); off += 128 * 64 / 2;   // bf16 W3^T
  int*   csr    = wsi + off; off += (size_t)((e + 3) & ~3);
  float* xs     = wsf + off; off += (size_t)((n * 7 + 3) & ~3);
  off = (off + 3) & ~(size_t)3;
  i32x2* stage  = (i32x2*)(wsi + off); off += (size_t)8 * CAP * 2;
  float* bufA   = wsf + off; off += (size_t)n * 128;
  float* bufB   = wsf + off; off += (size_t)n * 128;

  // bf16 tensors alias fp32 buffers (dataflow strictly serialized):
  unsigned short* t2 = (unsigned short*)bufB;   // agg7g1 out (dinv-scaled)
  unsigned short* a2 = (unsigned short*)bufA;   // agg128 out
  unsigned short* h2 = (unsigned short*)bufB;   // gemm2 out
  unsigned short* t3 = (unsigned short*)bufA;   // gemm3 out (dinv-scaled)

  const int* src = eidx;       // edge_index[0]
  const int* dst = eidx + e;   // edge_index[1]

  const int nb = (n + 255) / 256;
  const int wsize = (n + 7) / 8;

  // setup + CSR build (fused count+partition, then scan, then windowed scatter)
  k_misc<<<nb, 256, 0, stream>>>(deg, bkcnt, sums, W2, wb2t, W3, wb3t, n, G);
  k_partA<<<(e + 1023) / 1024, 256, 0, stream>>>(src, dst, deg, bkcnt, stage, e, wsize, CAP);
  k_scan1<<<nb, 256, 0, stream>>>(deg, rp, psum, x, dinv, xs, n);
  k_scan2<<<1, 256, 0, stream>>>(psum, nb);
  k_scan3<<<nb, 256, 0, stream>>>(rp, cursor, psum, n, e);
  const int nc = 128;
  k_scatB<<<8 * nc, 256, 0, stream>>>(stage, bkcnt, cursor, csr, CAP, nc);

  // layer 1 (fused): AGG(xs) + @W1 + b1, relu, dinv-scale -> bf16 t2
  k_agg7g1<<<(n + 3) / 4, 256, 0, stream>>>(xs, csr, rp, dinv, W1, b1, t2, n);

  // layer 2: AGG(t2) -> a2 bf16, then MFMA @W2 + b2, relu -> h2 bf16
  k_agg128<<<((size_t)n * 32 + 255) / 256, 256, 0, stream>>>(t2, csr, rp, dinv, a2, n);
  k_gemm2<<<(n + 63) / 64, 256, 0, stream>>>(a2, wb2t, b2, h2, n);

  // layer 3: MFMA h2 @ W3, dinv-scale -> t3 bf16, then AGG + b3 -> d_out
  k_gemm3<<<(n + 63) / 64, 256, 0, stream>>>(h2, wb3t, dinv, t3, n);
  k_agg64b<<<((size_t)n * 16 + 255) / 256, 256, 0, stream>>>(t3, csr, rp, dinv, b3, out, n);

  // mean pool -> d_out tail (node-parallel + finalize)
  const int waves = (n + 15) / 16;
  k_pool1<<<(waves * 64 + 255) / 256, 256, 0, stream>>>(out, batch, sums, n);
  k_pool2<<<G, 64, 0, stream>>>(sums, batch, out + (size_t)n * 64, n);
}